// Round 11
// baseline (277.246 us; speedup 1.0000x reference)
//
#include <hip/hip_runtime.h>
#include <hip/hip_bf16.h>
#include <math.h>

#define DIM 768
#define NTOK 4096   // B*N = 2*2048
#define SEQ 2048
#define HEADS 12
#define HD 64

using bf16x8 = __attribute__((ext_vector_type(8))) __bf16;
using bf16x4 = __attribute__((ext_vector_type(4))) __bf16;
using short4v = __attribute__((ext_vector_type(4))) short;
using f32x4  = __attribute__((ext_vector_type(4))) float;
typedef unsigned short u16;

#define KEXPF 0.18033688011112042f  // log2(e)/8

__device__ inline u16 f2bf(float f) {
  union { float f; unsigned u; } v; v.f = f;
  unsigned r = v.u + 0x7fffu + ((v.u >> 16) & 1u);  // RNE
  return (u16)(r >> 16);
}

// packed f32x2 -> bf16x2 (v_cvt_pk_bf16_f32)
__device__ inline void pk2bf(float a, float b, u16* o0, u16* o1) {
  union { __hip_bfloat162 h; u16 u[2]; } cv;
  cv.h = __float22bfloat162_rn(make_float2(a, b));
  *o0 = cv.u[0];
  *o1 = cv.u[1];
}

// packed f32x2 -> one u32 of 2 bf16 (lo = a, hi = b)
__device__ inline unsigned pku32(float a, float b) {
  union { __hip_bfloat162 h; unsigned u; } cv;
  cv.h = __float22bfloat162_rn(make_float2(a, b));
  return cv.u;
}

// GELU, sigmoid form: x*sigmoid(1.5957691x + 0.0713548x^3); |err| < ~3e-3.
__device__ inline float gelu_t(float x) {
  float z = x * (1.5957691216f + 0.0713548162f * x * x);
  return x / (1.0f + __expf(-z));
}

// async global->LDS DMA, 16 B per lane; LDS dest = wave-uniform base + lane*16
__device__ inline void gl_lds16(const u16* g, u16* l) {
  __builtin_amdgcn_global_load_lds(
      (const __attribute__((address_space(1))) unsigned int*)g,
      (__attribute__((address_space(3))) unsigned int*)l, 16, 0, 0);
}

// ---------------- LayerNorm: fp32 in -> bf16 out ----------------
__global__ __launch_bounds__(256) void ln_kernel(const float* __restrict__ x,
                                                 const float* __restrict__ w,
                                                 const float* __restrict__ b,
                                                 u16* __restrict__ y) {
  int row = blockIdx.x;
  int t = threadIdx.x;
  const float* xr = x + (size_t)row * DIM;
  float v0 = xr[t], v1 = xr[t + 256], v2 = xr[t + 512];
  float s = v0 + v1 + v2;
  float q = v0 * v0 + v1 * v1 + v2 * v2;
  for (int o = 32; o > 0; o >>= 1) {
    s += __shfl_down(s, o, 64);
    q += __shfl_down(q, o, 64);
  }
  __shared__ float ws_[4], wq_[4], mb[2];
  int wid = t >> 6;
  if ((t & 63) == 0) { ws_[wid] = s; wq_[wid] = q; }
  __syncthreads();
  if (t == 0) {
    float S = ws_[0] + ws_[1] + ws_[2] + ws_[3];
    float Q = wq_[0] + wq_[1] + wq_[2] + wq_[3];
    float mean = S * (1.0f / DIM);
    float var = Q * (1.0f / DIM) - mean * mean;
    mb[0] = mean;
    mb[1] = rsqrtf(var + 1e-5f);
  }
  __syncthreads();
  float mean = mb[0], rstd = mb[1];
  u16* yr = y + (size_t)row * DIM;
  yr[t]       = f2bf((v0 - mean) * rstd * w[t]       + b[t]);
  yr[t + 256] = f2bf((v1 - mean) * rstd * w[t + 256] + b[t + 256]);
  yr[t + 512] = f2bf((v2 - mean) * rstd * w[t + 512] + b[t + 512]);
}

// -------- fused split-K reduce + residual + bias -> x2 (fp32) + LN -> h (bf16)
__global__ __launch_bounds__(256) void redln_kernel(
    const float* __restrict__ P0, const float* __restrict__ P1,
    const float* __restrict__ bias, const float* __restrict__ res,
    float* __restrict__ x2, const float* __restrict__ lnw,
    const float* __restrict__ lnb, u16* __restrict__ y) {
  int row = blockIdx.x;
  int t = threadIdx.x;
  size_t off = (size_t)row * DIM;
  float v[3];
#pragma unroll
  for (int k = 0; k < 3; ++k) {
    int c = t + k * 256;
    v[k] = P0[off + c] + P1[off + c] + bias[c] + res[off + c];
    x2[off + c] = v[k];
  }
  float s = v[0] + v[1] + v[2];
  float q = v[0] * v[0] + v[1] * v[1] + v[2] * v[2];
  for (int o = 32; o > 0; o >>= 1) {
    s += __shfl_down(s, o, 64);
    q += __shfl_down(q, o, 64);
  }
  __shared__ float ws_[4], wq_[4], mb[2];
  int wid = t >> 6;
  if ((t & 63) == 0) { ws_[wid] = s; wq_[wid] = q; }
  __syncthreads();
  if (t == 0) {
    float S = ws_[0] + ws_[1] + ws_[2] + ws_[3];
    float Q = wq_[0] + wq_[1] + wq_[2] + wq_[3];
    float mean = S * (1.0f / DIM);
    float var = Q * (1.0f / DIM) - mean * mean;
    mb[0] = mean;
    mb[1] = rsqrtf(var + 1e-5f);
  }
  __syncthreads();
  float mean = mb[0], rstd = mb[1];
#pragma unroll
  for (int k = 0; k < 3; ++k) {
    int c = t + k * 256;
    y[off + c] = f2bf((v[k] - mean) * rstd * lnw[c] + lnb[c]);
  }
}

// ---------------- all 4 weight converts in one launch (dims compile-time) ----
__global__ __launch_bounds__(256) void wcvt_all(
    const float* __restrict__ W0, const float* __restrict__ W1,
    const float* __restrict__ W2, const float* __restrict__ W3,
    u16* __restrict__ T0, u16* __restrict__ T1,
    u16* __restrict__ T2, u16* __restrict__ T3) {
  int id = blockIdx.x;
  const float* W; u16* Wt; int K, N, local;
  if (id < 1728)      { W = W0; Wt = T0; K = 768;  N = 2304; local = id; }
  else if (id < 2304) { W = W1; Wt = T1; K = 768;  N = 768;  local = id - 1728; }
  else if (id < 4608) { W = W2; Wt = T2; K = 768;  N = 3072; local = id - 2304; }
  else                { W = W3; Wt = T3; K = 3072; N = 768;  local = id - 4608; }
  int ntiles = N / 32;
  int n0 = (local % ntiles) * 32, k0 = (local / ntiles) * 32;
  __shared__ float tile[32][33];
  int tid = threadIdx.x;
  int c = tid & 31, r8 = tid >> 5;
#pragma unroll
  for (int p = 0; p < 4; ++p) {
    int k = r8 + p * 8;
    tile[k][c] = W[(size_t)(k0 + k) * N + n0 + c];
  }
  __syncthreads();
#pragma unroll
  for (int p = 0; p < 4; ++p) {
    int n = r8 + p * 8;
    Wt[(size_t)(n0 + n) * K + k0 + c] = f2bf(tile[c][n]);
  }
}

// ---------------- V transpose: qkvB V-slice -> vT[b][v][j] ----------------
__global__ __launch_bounds__(256) void vtr_kernel(const u16* __restrict__ qkvB,
                                                  u16* __restrict__ vT) {
  __shared__ u16 tile[32][33];
  int v0 = blockIdx.x * 32, j0 = blockIdx.y * 32, b = blockIdx.z;
  int tid = threadIdx.x;
  int c = tid & 31, r8 = tid >> 5;
#pragma unroll
  for (int p = 0; p < 4; ++p) {
    int r = r8 + p * 8;
    tile[r][c] = qkvB[((size_t)(b * SEQ + j0 + r)) * 2304 + 1536 + v0 + c];
  }
  __syncthreads();
#pragma unroll
  for (int p = 0; p < 4; ++p) {
    int r = r8 + p * 8;
    vT[((size_t)(b * 768 + v0 + r)) * SEQ + j0 + c] = tile[c][r];
  }
}

// ---------------- bf16 MFMA GEMM (full-K): Cb = act(A * Bt^T + bias) --------
// R8 config (kept): BK=32 triple-buffer, 48 KB LDS, counted vmcnt, prefetch
// distance 2. XCD-aware bijective swizzle.
__global__ __launch_bounds__(256) void bgemm_kernel(
    const u16* __restrict__ A, const u16* __restrict__ Bt,
    const float* __restrict__ bias, u16* __restrict__ Cb,
    int M, int N, int K, int act, int scaleq) {
  __shared__ __align__(16) u16 Asl[3][128 * 32];
  __shared__ __align__(16) u16 Bsl[3][128 * 32];
  int nwg = gridDim.x * gridDim.y;
  int bid = blockIdx.y * gridDim.x + blockIdx.x;
  int swz = (bid & 7) * (nwg >> 3) + (bid >> 3);
  int bx = swz % gridDim.x, by = swz / gridDim.x;
  int tid = threadIdx.x;
  int lane = tid & 63, wave = tid >> 6;
  int wm = wave >> 1, wn = wave & 1;
  int bm = by * 128, bn = bx * 128;
  int l15 = lane & 15, quad = lane >> 4;
  int srow4 = lane >> 2;                        // 0..15: row within 16-row chunk
  int gux = (lane & 3) ^ ((srow4 + (srow4 >> 2)) & 3);  // swizzled global unit

  f32x4 acc[4][4] = {};
  const u16* Ap = A + (size_t)(bm + wave * 16 + srow4) * K + gux * 8;
  const u16* Bp = Bt + (size_t)(bn + wave * 16 + srow4) * K + gux * 8;
  int fx = (l15 + (l15 >> 2)) & 3;              // f(read row)
  int nk = K >> 5;

  auto STAGE = [&](int k0, int sel) {
#pragma unroll
    for (int p = 0; p < 2; ++p)
      gl_lds16(Ap + (size_t)(p * 64) * K + k0, &Asl[sel][(wave * 16 + p * 64) * 32]);
#pragma unroll
    for (int p = 0; p < 2; ++p)
      gl_lds16(Bp + (size_t)(p * 64) * K + k0, &Bsl[sel][(wave * 16 + p * 64) * 32]);
  };

  STAGE(0, 0);
  STAGE(32, 1);
  STAGE(64, 2);
  asm volatile("s_waitcnt vmcnt(8)" ::: "memory");  // tile 0's 4 loads done
  __builtin_amdgcn_s_barrier();

  int sel = 0;
  for (int t = 0; t < nk; ++t) {
    bf16x8 af[4], bfr[4];
#pragma unroll
    for (int i = 0; i < 4; ++i) {
      af[i]  = *(const bf16x8*)&Asl[sel][(wm * 64 + i * 16 + l15) * 32 + (quad ^ fx) * 8];
      bfr[i] = *(const bf16x8*)&Bsl[sel][(wn * 64 + i * 16 + l15) * 32 + (quad ^ fx) * 8];
    }
#pragma unroll
    for (int i = 0; i < 4; ++i)
#pragma unroll
      for (int j = 0; j < 4; ++j)
        acc[i][j] = __builtin_amdgcn_mfma_f32_16x16x32_bf16(af[i], bfr[j], acc[i][j], 0, 0, 0);
    if (t == nk - 1) break;
    __builtin_amdgcn_sched_barrier(0);
    __builtin_amdgcn_s_barrier();        // A: all reads of sel done
    __builtin_amdgcn_sched_barrier(0);
    if (t + 3 < nk) {
      STAGE((t + 3) << 5, sel);
      asm volatile("s_waitcnt vmcnt(8)" ::: "memory");  // retire t+1's 4 loads
    } else if (t + 2 < nk) {
      asm volatile("s_waitcnt vmcnt(4)" ::: "memory");  // retire t+1's 4 loads
    } else {
      asm volatile("s_waitcnt vmcnt(0)" ::: "memory");
    }
    __builtin_amdgcn_sched_barrier(0);
    __builtin_amdgcn_s_barrier();        // B: t+1 data visible
    __builtin_amdgcn_sched_barrier(0);
    sel = (sel == 2) ? 0 : sel + 1;
  }

#pragma unroll
  for (int i = 0; i < 4; ++i) {
#pragma unroll
    for (int j = 0; j < 4; ++j) {
      int n = bn + wn * 64 + j * 16 + l15;
      float bv = bias[n];
      float cs = (scaleq && n < 768) ? KEXPF : 1.0f;
      float val[4];
#pragma unroll
      for (int r = 0; r < 4; ++r) {
        float v = (acc[i][j][r] + bv) * cs;
        val[r] = act ? gelu_t(v) : v;
      }
      u16 c0, c1, c2, c3;
      pk2bf(val[0], val[1], &c0, &c1);
      pk2bf(val[2], val[3], &c2, &c3);
      size_t mbase = (size_t)(bm + wm * 64 + i * 16 + quad * 4) * N + n;
      Cb[mbase]         = c0;
      Cb[mbase + N]     = c1;
      Cb[mbase + 2 * N] = c2;
      Cb[mbase + 3 * N] = c3;
    }
  }
}

// ---------------- bf16 MFMA GEMM, split-K x2, 128x64 tile, BK=64 ------------
// R5 structure kept: counted-vmcnt double-buffer, 48 KB LDS (3 blocks/CU).
__global__ __launch_bounds__(256) void bgemm_splitk(
    const u16* __restrict__ A, const u16* __restrict__ Bt,
    float* __restrict__ P0, float* __restrict__ P1,
    int M, int N, int K) {
  __shared__ __align__(16) u16 Asl[2][128 * 64];
  __shared__ __align__(16) u16 Bsl[2][64 * 64];
  int nwg = gridDim.x * gridDim.y;
  int bid = blockIdx.y * gridDim.x + blockIdx.x;
  int swz = (bid & 7) * (nwg >> 3) + (bid >> 3);
  int bx = swz % gridDim.x, by = swz / gridDim.x;
  int tid = threadIdx.x;
  int lane = tid & 63, wave = tid >> 6;
  int wm = wave >> 1, wn = wave & 1;
  int bm = by * 128, bn = bx * 64;
  int l15 = lane & 15, quad = lane >> 4;
  int sm8 = tid >> 3;
  int kgx = (tid & 7) ^ (sm8 & 7);
  int half = K >> 1;
  int kbeg = blockIdx.z * half;

  f32x4 acc[4][2] = {};
  const u16* Ap = A + (size_t)(bm + sm8) * K + kbeg + kgx * 8;
  const u16* Bp = Bt + (size_t)(bn + sm8) * K + kbeg + kgx * 8;
  int xr = l15 & 7;
  int nk = half >> 6;

  auto STAGE = [&](int k0, int sel) {
#pragma unroll
    for (int p = 0; p < 4; ++p)
      gl_lds16(Ap + (size_t)(p * 32) * K + k0, &Asl[sel][(wave * 8 + p * 32) * 64]);
#pragma unroll
    for (int p = 0; p < 2; ++p)
      gl_lds16(Bp + (size_t)(p * 32) * K + k0, &Bsl[sel][(wave * 8 + p * 32) * 64]);
  };

  STAGE(0, 0);
  if (nk > 1) STAGE(64, 1);
  asm volatile("s_waitcnt vmcnt(6)" ::: "memory");
  __builtin_amdgcn_s_barrier();

  for (int t = 0; t < nk; ++t) {
    int sel = t & 1;
#pragma unroll
    for (int ks = 0; ks < 2; ++ks) {
      int pu = ((ks << 2) + quad) ^ xr;
      bf16x8 af[4], bfr[2];
#pragma unroll
      for (int i = 0; i < 4; ++i)
        af[i] = *(const bf16x8*)&Asl[sel][(wm * 64 + i * 16 + l15) * 64 + pu * 8];
#pragma unroll
      for (int j = 0; j < 2; ++j)
        bfr[j] = *(const bf16x8*)&Bsl[sel][(wn * 32 + j * 16 + l15) * 64 + pu * 8];
#pragma unroll
      for (int i = 0; i < 4; ++i)
#pragma unroll
        for (int j = 0; j < 2; ++j)
          acc[i][j] = __builtin_amdgcn_mfma_f32_16x16x32_bf16(af[i], bfr[j], acc[i][j], 0, 0, 0);
    }
    if (t == nk - 1) break;
    __builtin_amdgcn_sched_barrier(0);
    __builtin_amdgcn_s_barrier();        // A
    __builtin_amdgcn_sched_barrier(0);
    if (t + 2 < nk) {
      STAGE((t + 2) << 6, sel);
      asm volatile("s_waitcnt vmcnt(6)" ::: "memory");
    } else {
      asm volatile("s_waitcnt vmcnt(0)" ::: "memory");
    }
    __builtin_amdgcn_sched_barrier(0);
    __builtin_amdgcn_s_barrier();        // B
    __builtin_amdgcn_sched_barrier(0);
  }

  float* P = blockIdx.z ? P1 : P0;
#pragma unroll
  for (int i = 0; i < 4; ++i) {
#pragma unroll
    for (int j = 0; j < 2; ++j) {
      int n = bn + wn * 32 + j * 16 + l15;
#pragma unroll
      for (int r = 0; r < 4; ++r) {
        int m = bm + wm * 64 + i * 16 + quad * 4 + r;
        P[(size_t)m * N + n] = acc[i][j][r];
      }
    }
  }
}

// ---------------- split-K reduce: O = P0 + P1 + bias + res ------------------
__global__ __launch_bounds__(256) void red_kernel(
    const float* P0, const float* __restrict__ P1,
    const float* __restrict__ bias, const float* __restrict__ res,
    float* O, int Ncols) {
  int i = blockIdx.x * 256 + threadIdx.x;
  float4 a = ((const float4*)P0)[i];
  float4 b = ((const float4*)P1)[i];
  float4 r = ((const float4*)res)[i];
  int col = (i * 4) % Ncols;
  float4 bi = *(const float4*)&bias[col];
  float4 o;
  o.x = a.x + b.x + r.x + bi.x;
  o.y = a.y + b.y + r.y + bi.y;
  o.z = a.z + b.z + r.z + bi.z;
  o.w = a.w + b.w + r.w + bi.w;
  ((float4*)O)[i] = o;
}

// ---------------- 8-wave MFMA flash attention, (ws,js)-partitioned ----------
// R11: (a) SINGLE barrier per tile via triple-buffered K/V (48 KB arena, still
// 3 blocks/CU): prefetch t+2 -> slot (t+2)%3, disjoint from cur (t%3) and next
// ((t+1)%3). Safety: a wave in tile t passed barrier(t-1) => ALL waves finished
// tile t-1's reads of slot (t-1)%3 == (t+2)%3 => overwrite safe. vmcnt(2)
// before the barrier retires t+1's 2 loads (issue order) -> barrier publishes
// them. 32 barrier convergences deleted vs R10. Q stages through V[2] (dead
// after frag-load; one-time extra __syncthreads protects it).
// (b) full-sector epilogue: d-chunks processed in PAIRS (LDSw 33.8 KB), each
// lane writes uint2, 8 lanes = 64 B contiguous per row (R10 wrote 32 B halves
// -> 2x write amplification, WRITE_SIZE 13.8 MB).
#define LQP 33
__global__ __launch_bounds__(512, 6) void attn_kernel(const u16* __restrict__ qkv,
                                                      const u16* __restrict__ vT,
                                                      u16* __restrict__ out) {
  __shared__ __align__(16) char arena[49152];
  u16* Kb3 = (u16*)arena;                 // [3][64x64] u16 (24 KB)
  u16* Vb3 = (u16*)(arena + 24576);       // [3][64x64] u16 (24 KB)

  int nwg = gridDim.x * gridDim.y * gridDim.z;
  int bid = (blockIdx.z * gridDim.y + blockIdx.y) * gridDim.x + blockIdx.x;
  int swz = (bid & 7) * (nwg >> 3) + (bid >> 3);
  int bx = swz % gridDim.x;
  int rem = swz / gridDim.x;
  int h = rem % gridDim.y, b = rem / gridDim.y;

  int tid = threadIdx.x;
  int lane = tid & 63, wave = tid >> 6;   // 8 waves
  int ws = wave & 1, js = wave >> 1;      // q-half, j-stripe
  int l15 = lane & 15, quad = lane >> 4;
  int qt = bx * 64;
  size_t base = (size_t)b * SEQ;
  int srow = lane >> 3;                 // 0..7 within an 8-row DMA chunk
  int sux = (lane & 7) ^ (srow & 7);    // XOR-swizzled global 16B col-unit
  int r0 = wave * 8;                    // this wave's staging row base (8 rows)
  const u16* qbase = qkv + (base + qt) * 2304 + h * HD;
  const u16* kbase = qkv + base * 2304 + 768 + h * HD;
  const u16* vbase = vT + ((size_t)(b * HEADS + h) * HD) * SEQ;

  // prologue: Q -> V[2] (temp), K/V tiles 0,1 -> slots 0,1
  gl_lds16(qbase + (size_t)(r0 + srow) * 2304 + sux * 8, Vb3 + 2 * 4096 + r0 * 64);
  gl_lds16(kbase + (size_t)(r0 + srow) * 2304 + sux * 8, Kb3 + r0 * 64);
  gl_lds16(vbase + (size_t)(r0 + srow) * SEQ + sux * 8, Vb3 + r0 * 64);
  gl_lds16(kbase + (size_t)(64 + r0 + srow) * 2304 + sux * 8, Kb3 + 4096 + r0 * 64);
  gl_lds16(vbase + (size_t)(r0 + srow) * SEQ + 64 + sux * 8, Vb3 + 4096 + r0 * 64);
  __syncthreads();   // full drain: Q + tiles 0,1 visible

  int xr = l15 & 7;
  // Q-frags: q-group g (rows ws*32 + g*16 + l15), k-step s (32 k each)
  const u16* Qtmp = Vb3 + 2 * 4096;
  bf16x8 qf[2][2];
#pragma unroll
  for (int g = 0; g < 2; ++g)
#pragma unroll
    for (int s = 0; s < 2; ++s)
      qf[g][s] = *(const bf16x8*)&Qtmp[(ws * 32 + g * 16 + l15) * 64 + ((s * 4 + quad) ^ xr) * 8];
  __syncthreads();   // ALL waves' Q-frag reads done before V[2] is overwritten
                     // by tile-2's prefetch (issued in tile-0 body below)

  // tile-invariant LDS element offsets (stripe js)
  int koff0 = (js * 16 + l15) * 64 + ((quad ^ xr)) * 8;
  int koff1 = (js * 16 + l15) * 64 + (((4 + quad) ^ xr)) * 8;
  int voff[4];
#pragma unroll
  for (int dg = 0; dg < 4; ++dg)
    voff[dg] = (dg * 16 + l15) * 64 + (((2 * js + (quad >> 1)) ^ xr)) * 8 + (quad & 1) * 4;

  f32x4 oT[4][2] = {};   // [dg][g] : O^T tiles (d rows, q cols), js-partial
  f32x4 oT1[2] = {};     // [g] : ones-row accumulators (stripe row-sums of P)
  const short4v ONES = {(short)0x3F80, (short)0x3F80, (short)0x3F80, (short)0x3F80};
  int cur = 0;

  for (int t = 0; t < 32; ++t) {
    const u16* Kb = Kb3 + cur * 4096;
    const u16* Vb = Vb3 + cur * 4096;

    // QK^T: S^T[j-stripe 16][q-half 32] ; lane: j=16js+quad*4+r, q=ws*32+16g+l15
    f32x4 sT[2] = {};
    __builtin_amdgcn_s_setprio(1);
    {
      bf16x8 ak = *(const bf16x8*)&Kb[koff0];
#pragma unroll
      for (int g = 0; g < 2; ++g)
        sT[g] = __builtin_amdgcn_mfma_f32_16x16x32_bf16(ak, qf[g][0], sT[g], 0, 0, 0);
      bf16x8 ak1 = *(const bf16x8*)&Kb[koff1];
#pragma unroll
      for (int g = 0; g < 2; ++g)
        sT[g] = __builtin_amdgcn_mfma_f32_16x16x32_bf16(ak1, qf[g][1], sT[g], 0, 0, 0);
    }
    __builtin_amdgcn_s_setprio(0);

    // softmax (max-free, Q pre-scaled): p = 2^s ; pack -> x16 B-frags
    short4v pb[2];
#pragma unroll
    for (int g = 0; g < 2; ++g) {
      float p0 = __builtin_amdgcn_exp2f(sT[g][0]);
      float p1 = __builtin_amdgcn_exp2f(sT[g][1]);
      float p2 = __builtin_amdgcn_exp2f(sT[g][2]);
      float p3 = __builtin_amdgcn_exp2f(sT[g][3]);
      union { unsigned u[2]; short4v s; } cv;
      cv.u[0] = pku32(p0, p1);
      cv.u[1] = pku32(p2, p3);
      pb[g] = cv.s;
    }

    // PV: oT[dg][g] += V^T[d-block][stripe] * P^T[stripe][q-group]
    // + ones row: oT1[g] += 1s * P^T  (stripe row-sum -> l partials)
    short4v av[4];
#pragma unroll
    for (int dg = 0; dg < 4; ++dg)
      av[dg] = *(const short4v*)&Vb[voff[dg]];
    __builtin_amdgcn_s_setprio(1);
#pragma unroll
    for (int dg = 0; dg < 4; ++dg)
#pragma unroll
      for (int g = 0; g < 2; ++g)
        oT[dg][g] = __builtin_amdgcn_mfma_f32_16x16x16bf16_1k(av[dg], pb[g], oT[dg][g], 0, 0, 0);
#pragma unroll
    for (int g = 0; g < 2; ++g)
      oT1[g] = __builtin_amdgcn_mfma_f32_16x16x16bf16_1k(ONES, pb[g], oT1[g], 0, 0, 0);
    __builtin_amdgcn_s_setprio(0);

    __builtin_amdgcn_sched_barrier(0);
    if (t < 30) {  // prefetch tile t+2 -> slot (cur+2)%3 (== slot of t-1,
                   // whose reads all waves finished before barrier(t-1))
      int pf = cur + 2; if (pf >= 3) pf -= 3;
      size_t kt2 = (size_t)(t + 2) * 64;
      gl_lds16(kbase + (kt2 + r0 + srow) * 2304 + sux * 8, Kb3 + pf * 4096 + r0 * 64);
      gl_lds16(vbase + (size_t)(r0 + srow) * SEQ + kt2 + sux * 8, Vb3 + pf * 4096 + r0 * 64);
      asm volatile("s_waitcnt vmcnt(2)" ::: "memory");  // retire t+1's 2 loads
    } else {
      asm volatile("s_waitcnt vmcnt(0)" ::: "memory");
    }
    __builtin_amdgcn_sched_barrier(0);
    __builtin_amdgcn_s_barrier();          // publish t+1; frees slot (t-1)%3
    __builtin_amdgcn_sched_barrier(0);
    cur = (cur == 2) ? 0 : cur + 1;
  }

  // ---- epilogue: reduce js-partial O^T + l across the 4 js waves ----
  // (t=31's barrier guarantees all K/V reads done -> arena reusable)
  float* LDSw = (float*)arena;             // [2 ws][4 js][32 d][LQP] (33.8 KB)
  float* lsd  = (float*)(arena + 33792);   // [2 ws][4 js][32 q] (1 KB)
  if (lane < 16) {
#pragma unroll
    for (int g = 0; g < 2; ++g)
      lsd[(ws * 4 + js) * 32 + g * 16 + lane] = oT1[g][0];
  }
  // read-phase map: qq = q-row (8 lanes each), lane8*4 = d base within the
  // 32-d pass -> each lane writes uint2; 8 lanes = 64 B contiguous (full sector)
  int qq = tid >> 3, lane8 = tid & 7;
  int ws2 = qq >> 5, qx = qq & 31;
  float linv = 0.f;
#pragma unroll
  for (int p = 0; p < 2; ++p) {
    // write phase: wave (ws,js) writes oT chunks 2p, 2p+1
#pragma unroll
    for (int dgl = 0; dgl < 2; ++dgl)
#pragma unroll
      for (int g = 0; g < 2; ++g)
#pragma unroll
        for (int r = 0; r < 4; ++r)
          LDSw[((ws * 4 + js) * 32 + dgl * 16 + quad * 4 + r) * LQP + g * 16 + l15] =
              oT[2 * p + dgl][g][r];
    __syncthreads();
    if (p == 0) {
      float L = lsd[(ws2 * 4 + 0) * 32 + qx] + lsd[(ws2 * 4 + 1) * 32 + qx] +
                lsd[(ws2 * 4 + 2) * 32 + qx] + lsd[(ws2 * 4 + 3) * 32 + qx];
      linv = 1.0f / L;
    }
    // sum phase: thread (qq, lane8) -> q = qq, d = p*32 + lane8*4 + {0..3}
    float sv[4];
#pragma unroll
    for (int i = 0; i < 4; ++i) {
      int dloc = lane8 * 4 + i;
      float a = LDSw[((ws2 * 4 + 0) * 32 + dloc) * LQP + qx] +
                LDSw[((ws2 * 4 + 1) * 32 + dloc) * LQP + qx] +
                LDSw[((ws2 * 4 + 2) * 32 + dloc) * LQP + qx] +
                LDSw[((ws2 * 4 + 3) * 32 + dloc) * LQP + qx];
      sv[i] = a * linv;
    }
    size_t addr = (base + qt + qq) * DIM + h * HD + p * 32 + lane8 * 4;
    uint2 pk;
    pk.x = pku32(sv[0], sv[1]);
    pk.y = pku32(sv[2], sv[3]);
    *(uint2*)&out[addr] = pk;
    __syncthreads();  // before next pass reuses LDSw
  }
}

extern "C" void kernel_launch(void* const* d_in, const int* in_sizes, int n_in,
                              void* d_out, int out_size, void* d_ws, size_t ws_size,
                              hipStream_t stream) {
  const float* x     = (const float*)d_in[0];
  const float* ln1w  = (const float*)d_in[1];
  const float* ln1b  = (const float*)d_in[2];
  const float* qkvw  = (const float*)d_in[3];
  const float* qkvbi = (const float*)d_in[4];
  const float* projw = (const float*)d_in[5];
  const float* projb = (const float*)d_in[6];
  const float* ln2w  = (const float*)d_in[7];
  const float* ln2b  = (const float*)d_in[8];
  const float* l1w   = (const float*)d_in[9];
  const float* l1b   = (const float*)d_in[10];
  const float* l2w   = (const float*)d_in[11];
  const float* l2b   = (const float*)d_in[12];
  float* out = (float*)d_out;

  char* w = (char*)d_ws;
  u16*   h     = (u16*)w;   w += (size_t)NTOK * DIM * 2;          // 6.3 MB
  u16*   qkvB  = (u16*)w;                                         // 18.9 MB (union)
  u16*   mid   = (u16*)w;   w += (size_t)NTOK * 3072 * 2;         // 25.2 MB union
  u16*   attnb = (u16*)w;   w += (size_t)NTOK * DIM * 2;          // 6.3 MB
  float* x2    = (float*)w; w += (size_t)NTOK * DIM * 4;          // 12.6 MB
  u16*   vTb   = (u16*)w;   w += (size_t)NTOK * DIM * 2;          // 6.3 MB
  u16*   qkvwt = (u16*)w;   w += (size_t)DIM * 2304 * 2;
  u16*   projwt= (u16*)w;   w += (size_t)DIM * DIM * 2;
  u16*   l1wt  = (u16*)w;   w += (size_t)DIM * 3072 * 2;
  u16*   l2wt  = (u16*)w;   w += (size_t)3072 * DIM * 2;
  float* Pbuf  = (float*)w; w += (size_t)NTOK * DIM * 4;          // 12.6 MB (split-K P1)

  wcvt_all<<<6912, 256, 0, stream>>>(qkvw, projw, l1w, l2w,
                                     qkvwt, projwt, l1wt, l2wt);

  ln_kernel<<<NTOK, 256, 0, stream>>>(x, ln1w, ln1b, h);
  bgemm_kernel<<<dim3(2304 / 128, NTOK / 128), 256, 0, stream>>>(
      h, qkvwt, qkvbi, qkvB, NTOK, 2304, DIM, 0, 1);
  vtr_kernel<<<dim3(768 / 32, SEQ / 32, 2), 256, 0, stream>>>(qkvB, vTb);
  attn_kernel<<<dim3(SEQ / 64, HEADS, 2), 512, 0, stream>>>(qkvB, vTb, attnb);

  // proj: split-K x2 -> x2 + Pbuf; fused reduce(+bias+x residual) + LN2
  bgemm_splitk<<<dim3(DIM / 64, NTOK / 128, 2), 256, 0, stream>>>(
      attnb, projwt, x2, Pbuf, NTOK, DIM, DIM);
  redln_kernel<<<NTOK, 256, 0, stream>>>(x2, Pbuf, projb, x, x2, ln2w, ln2b, h);

  bgemm_kernel<<<dim3(3072 / 128, NTOK / 128), 256, 0, stream>>>(
      h, l1wt, l1b, mid, NTOK, 3072, DIM, 1, 0);

  // lin2: split-K x2 -> out + Pbuf; reduce adds bias + x2 residual
  bgemm_splitk<<<dim3(DIM / 64, NTOK / 128, 2), 256, 0, stream>>>(
      mid, l2wt, out, Pbuf, NTOK, DIM, 3072);
  red_kernel<<<NTOK * DIM / 1024, 256, 0, stream>>>(out, Pbuf, l2b, x2, out, DIM);
}

// Round 12
// 272.555 us; speedup vs baseline: 1.0172x; 1.0172x over previous
//
#include <hip/hip_runtime.h>
#include <hip/hip_bf16.h>
#include <math.h>

#define DIM 768
#define NTOK 4096   // B*N = 2*2048
#define SEQ 2048
#define HEADS 12
#define HD 64

using bf16x8 = __attribute__((ext_vector_type(8))) __bf16;
using bf16x4 = __attribute__((ext_vector_type(4))) __bf16;
using short4v = __attribute__((ext_vector_type(4))) short;
using f32x4  = __attribute__((ext_vector_type(4))) float;
typedef unsigned short u16;

#define KEXPF 0.18033688011112042f  // log2(e)/8

__device__ inline u16 f2bf(float f) {
  union { float f; unsigned u; } v; v.f = f;
  unsigned r = v.u + 0x7fffu + ((v.u >> 16) & 1u);  // RNE
  return (u16)(r >> 16);
}

// packed f32x2 -> bf16x2 (v_cvt_pk_bf16_f32)
__device__ inline void pk2bf(float a, float b, u16* o0, u16* o1) {
  union { __hip_bfloat162 h; u16 u[2]; } cv;
  cv.h = __float22bfloat162_rn(make_float2(a, b));
  *o0 = cv.u[0];
  *o1 = cv.u[1];
}

// packed f32x2 -> one u32 of 2 bf16 (lo = a, hi = b)
__device__ inline unsigned pku32(float a, float b) {
  union { __hip_bfloat162 h; unsigned u; } cv;
  cv.h = __float22bfloat162_rn(make_float2(a, b));
  return cv.u;
}

// GELU, sigmoid form: x*sigmoid(1.5957691x + 0.0713548x^3); |err| < ~3e-3.
__device__ inline float gelu_t(float x) {
  float z = x * (1.5957691216f + 0.0713548162f * x * x);
  return x / (1.0f + __expf(-z));
}

// async global->LDS DMA, 16 B per lane; LDS dest = wave-uniform base + lane*16
__device__ inline void gl_lds16(const u16* g, u16* l) {
  __builtin_amdgcn_global_load_lds(
      (const __attribute__((address_space(1))) unsigned int*)g,
      (__attribute__((address_space(3))) unsigned int*)l, 16, 0, 0);
}

// ---------------- LayerNorm: fp32 in -> bf16 out ----------------
__global__ __launch_bounds__(256) void ln_kernel(const float* __restrict__ x,
                                                 const float* __restrict__ w,
                                                 const float* __restrict__ b,
                                                 u16* __restrict__ y) {
  int row = blockIdx.x;
  int t = threadIdx.x;
  const float* xr = x + (size_t)row * DIM;
  float v0 = xr[t], v1 = xr[t + 256], v2 = xr[t + 512];
  float s = v0 + v1 + v2;
  float q = v0 * v0 + v1 * v1 + v2 * v2;
  for (int o = 32; o > 0; o >>= 1) {
    s += __shfl_down(s, o, 64);
    q += __shfl_down(q, o, 64);
  }
  __shared__ float ws_[4], wq_[4], mb[2];
  int wid = t >> 6;
  if ((t & 63) == 0) { ws_[wid] = s; wq_[wid] = q; }
  __syncthreads();
  if (t == 0) {
    float S = ws_[0] + ws_[1] + ws_[2] + ws_[3];
    float Q = wq_[0] + wq_[1] + wq_[2] + wq_[3];
    float mean = S * (1.0f / DIM);
    float var = Q * (1.0f / DIM) - mean * mean;
    mb[0] = mean;
    mb[1] = rsqrtf(var + 1e-5f);
  }
  __syncthreads();
  float mean = mb[0], rstd = mb[1];
  u16* yr = y + (size_t)row * DIM;
  yr[t]       = f2bf((v0 - mean) * rstd * w[t]       + b[t]);
  yr[t + 256] = f2bf((v1 - mean) * rstd * w[t + 256] + b[t + 256]);
  yr[t + 512] = f2bf((v2 - mean) * rstd * w[t + 512] + b[t + 512]);
}

// -------- fused split-K reduce + residual + bias -> x2 (fp32) + LN -> h (bf16)
__global__ __launch_bounds__(256) void redln_kernel(
    const float* __restrict__ P0, const float* __restrict__ P1,
    const float* __restrict__ bias, const float* __restrict__ res,
    float* __restrict__ x2, const float* __restrict__ lnw,
    const float* __restrict__ lnb, u16* __restrict__ y) {
  int row = blockIdx.x;
  int t = threadIdx.x;
  size_t off = (size_t)row * DIM;
  float v[3];
#pragma unroll
  for (int k = 0; k < 3; ++k) {
    int c = t + k * 256;
    v[k] = P0[off + c] + P1[off + c] + bias[c] + res[off + c];
    x2[off + c] = v[k];
  }
  float s = v[0] + v[1] + v[2];
  float q = v[0] * v[0] + v[1] * v[1] + v[2] * v[2];
  for (int o = 32; o > 0; o >>= 1) {
    s += __shfl_down(s, o, 64);
    q += __shfl_down(q, o, 64);
  }
  __shared__ float ws_[4], wq_[4], mb[2];
  int wid = t >> 6;
  if ((t & 63) == 0) { ws_[wid] = s; wq_[wid] = q; }
  __syncthreads();
  if (t == 0) {
    float S = ws_[0] + ws_[1] + ws_[2] + ws_[3];
    float Q = wq_[0] + wq_[1] + wq_[2] + wq_[3];
    float mean = S * (1.0f / DIM);
    float var = Q * (1.0f / DIM) - mean * mean;
    mb[0] = mean;
    mb[1] = rsqrtf(var + 1e-5f);
  }
  __syncthreads();
  float mean = mb[0], rstd = mb[1];
#pragma unroll
  for (int k = 0; k < 3; ++k) {
    int c = t + k * 256;
    y[off + c] = f2bf((v[k] - mean) * rstd * lnw[c] + lnb[c]);
  }
}

// ---------------- all 4 weight converts in one launch (dims compile-time) ----
__global__ __launch_bounds__(256) void wcvt_all(
    const float* __restrict__ W0, const float* __restrict__ W1,
    const float* __restrict__ W2, const float* __restrict__ W3,
    u16* __restrict__ T0, u16* __restrict__ T1,
    u16* __restrict__ T2, u16* __restrict__ T3) {
  int id = blockIdx.x;
  const float* W; u16* Wt; int K, N, local;
  if (id < 1728)      { W = W0; Wt = T0; K = 768;  N = 2304; local = id; }
  else if (id < 2304) { W = W1; Wt = T1; K = 768;  N = 768;  local = id - 1728; }
  else if (id < 4608) { W = W2; Wt = T2; K = 768;  N = 3072; local = id - 2304; }
  else                { W = W3; Wt = T3; K = 3072; N = 768;  local = id - 4608; }
  int ntiles = N / 32;
  int n0 = (local % ntiles) * 32, k0 = (local / ntiles) * 32;
  __shared__ float tile[32][33];
  int tid = threadIdx.x;
  int c = tid & 31, r8 = tid >> 5;
#pragma unroll
  for (int p = 0; p < 4; ++p) {
    int k = r8 + p * 8;
    tile[k][c] = W[(size_t)(k0 + k) * N + n0 + c];
  }
  __syncthreads();
#pragma unroll
  for (int p = 0; p < 4; ++p) {
    int n = r8 + p * 8;
    Wt[(size_t)(n0 + n) * K + k0 + c] = f2bf(tile[c][n]);
  }
}

// ---------------- V transpose: qkvB V-slice -> vT[b][v][j] ----------------
__global__ __launch_bounds__(256) void vtr_kernel(const u16* __restrict__ qkvB,
                                                  u16* __restrict__ vT) {
  __shared__ u16 tile[32][33];
  int v0 = blockIdx.x * 32, j0 = blockIdx.y * 32, b = blockIdx.z;
  int tid = threadIdx.x;
  int c = tid & 31, r8 = tid >> 5;
#pragma unroll
  for (int p = 0; p < 4; ++p) {
    int r = r8 + p * 8;
    tile[r][c] = qkvB[((size_t)(b * SEQ + j0 + r)) * 2304 + 1536 + v0 + c];
  }
  __syncthreads();
#pragma unroll
  for (int p = 0; p < 4; ++p) {
    int r = r8 + p * 8;
    vT[((size_t)(b * 768 + v0 + r)) * SEQ + j0 + c] = tile[c][r];
  }
}

// ---------------- bf16 MFMA GEMM (full-K): Cb = act(A * Bt^T + bias) --------
// R8 config (kept): BK=32 triple-buffer, 48 KB LDS, counted vmcnt, prefetch
// distance 2. XCD-aware bijective swizzle.
__global__ __launch_bounds__(256) void bgemm_kernel(
    const u16* __restrict__ A, const u16* __restrict__ Bt,
    const float* __restrict__ bias, u16* __restrict__ Cb,
    int M, int N, int K, int act, int scaleq) {
  __shared__ __align__(16) u16 Asl[3][128 * 32];
  __shared__ __align__(16) u16 Bsl[3][128 * 32];
  int nwg = gridDim.x * gridDim.y;
  int bid = blockIdx.y * gridDim.x + blockIdx.x;
  int swz = (bid & 7) * (nwg >> 3) + (bid >> 3);
  int bx = swz % gridDim.x, by = swz / gridDim.x;
  int tid = threadIdx.x;
  int lane = tid & 63, wave = tid >> 6;
  int wm = wave >> 1, wn = wave & 1;
  int bm = by * 128, bn = bx * 128;
  int l15 = lane & 15, quad = lane >> 4;
  int srow4 = lane >> 2;                        // 0..15: row within 16-row chunk
  int gux = (lane & 3) ^ ((srow4 + (srow4 >> 2)) & 3);  // swizzled global unit

  f32x4 acc[4][4] = {};
  const u16* Ap = A + (size_t)(bm + wave * 16 + srow4) * K + gux * 8;
  const u16* Bp = Bt + (size_t)(bn + wave * 16 + srow4) * K + gux * 8;
  int fx = (l15 + (l15 >> 2)) & 3;              // f(read row)
  int nk = K >> 5;

  auto STAGE = [&](int k0, int sel) {
#pragma unroll
    for (int p = 0; p < 2; ++p)
      gl_lds16(Ap + (size_t)(p * 64) * K + k0, &Asl[sel][(wave * 16 + p * 64) * 32]);
#pragma unroll
    for (int p = 0; p < 2; ++p)
      gl_lds16(Bp + (size_t)(p * 64) * K + k0, &Bsl[sel][(wave * 16 + p * 64) * 32]);
  };

  STAGE(0, 0);
  STAGE(32, 1);
  STAGE(64, 2);
  asm volatile("s_waitcnt vmcnt(8)" ::: "memory");  // tile 0's 4 loads done
  __builtin_amdgcn_s_barrier();

  int sel = 0;
  for (int t = 0; t < nk; ++t) {
    bf16x8 af[4], bfr[4];
#pragma unroll
    for (int i = 0; i < 4; ++i) {
      af[i]  = *(const bf16x8*)&Asl[sel][(wm * 64 + i * 16 + l15) * 32 + (quad ^ fx) * 8];
      bfr[i] = *(const bf16x8*)&Bsl[sel][(wn * 64 + i * 16 + l15) * 32 + (quad ^ fx) * 8];
    }
#pragma unroll
    for (int i = 0; i < 4; ++i)
#pragma unroll
      for (int j = 0; j < 4; ++j)
        acc[i][j] = __builtin_amdgcn_mfma_f32_16x16x32_bf16(af[i], bfr[j], acc[i][j], 0, 0, 0);
    if (t == nk - 1) break;
    __builtin_amdgcn_sched_barrier(0);
    __builtin_amdgcn_s_barrier();        // A: all reads of sel done
    __builtin_amdgcn_sched_barrier(0);
    if (t + 3 < nk) {
      STAGE((t + 3) << 5, sel);
      asm volatile("s_waitcnt vmcnt(8)" ::: "memory");  // retire t+1's 4 loads
    } else if (t + 2 < nk) {
      asm volatile("s_waitcnt vmcnt(4)" ::: "memory");  // retire t+1's 4 loads
    } else {
      asm volatile("s_waitcnt vmcnt(0)" ::: "memory");
    }
    __builtin_amdgcn_sched_barrier(0);
    __builtin_amdgcn_s_barrier();        // B: t+1 data visible
    __builtin_amdgcn_sched_barrier(0);
    sel = (sel == 2) ? 0 : sel + 1;
  }

#pragma unroll
  for (int i = 0; i < 4; ++i) {
#pragma unroll
    for (int j = 0; j < 4; ++j) {
      int n = bn + wn * 64 + j * 16 + l15;
      float bv = bias[n];
      float cs = (scaleq && n < 768) ? KEXPF : 1.0f;
      float val[4];
#pragma unroll
      for (int r = 0; r < 4; ++r) {
        float v = (acc[i][j][r] + bv) * cs;
        val[r] = act ? gelu_t(v) : v;
      }
      u16 c0, c1, c2, c3;
      pk2bf(val[0], val[1], &c0, &c1);
      pk2bf(val[2], val[3], &c2, &c3);
      size_t mbase = (size_t)(bm + wm * 64 + i * 16 + quad * 4) * N + n;
      Cb[mbase]         = c0;
      Cb[mbase + N]     = c1;
      Cb[mbase + 2 * N] = c2;
      Cb[mbase + 3 * N] = c3;
    }
  }
}

// ---------------- bf16 MFMA GEMM, split-K x2, 128x64 tile, BK=64 ------------
// R5 structure kept: counted-vmcnt double-buffer, 48 KB LDS (3 blocks/CU).
__global__ __launch_bounds__(256) void bgemm_splitk(
    const u16* __restrict__ A, const u16* __restrict__ Bt,
    float* __restrict__ P0, float* __restrict__ P1,
    int M, int N, int K) {
  __shared__ __align__(16) u16 Asl[2][128 * 64];
  __shared__ __align__(16) u16 Bsl[2][64 * 64];
  int nwg = gridDim.x * gridDim.y;
  int bid = blockIdx.y * gridDim.x + blockIdx.x;
  int swz = (bid & 7) * (nwg >> 3) + (bid >> 3);
  int bx = swz % gridDim.x, by = swz / gridDim.x;
  int tid = threadIdx.x;
  int lane = tid & 63, wave = tid >> 6;
  int wm = wave >> 1, wn = wave & 1;
  int bm = by * 128, bn = bx * 64;
  int l15 = lane & 15, quad = lane >> 4;
  int sm8 = tid >> 3;
  int kgx = (tid & 7) ^ (sm8 & 7);
  int half = K >> 1;
  int kbeg = blockIdx.z * half;

  f32x4 acc[4][2] = {};
  const u16* Ap = A + (size_t)(bm + sm8) * K + kbeg + kgx * 8;
  const u16* Bp = Bt + (size_t)(bn + sm8) * K + kbeg + kgx * 8;
  int xr = l15 & 7;
  int nk = half >> 6;

  auto STAGE = [&](int k0, int sel) {
#pragma unroll
    for (int p = 0; p < 4; ++p)
      gl_lds16(Ap + (size_t)(p * 32) * K + k0, &Asl[sel][(wave * 8 + p * 32) * 64]);
#pragma unroll
    for (int p = 0; p < 2; ++p)
      gl_lds16(Bp + (size_t)(p * 32) * K + k0, &Bsl[sel][(wave * 8 + p * 32) * 64]);
  };

  STAGE(0, 0);
  if (nk > 1) STAGE(64, 1);
  asm volatile("s_waitcnt vmcnt(6)" ::: "memory");
  __builtin_amdgcn_s_barrier();

  for (int t = 0; t < nk; ++t) {
    int sel = t & 1;
#pragma unroll
    for (int ks = 0; ks < 2; ++ks) {
      int pu = ((ks << 2) + quad) ^ xr;
      bf16x8 af[4], bfr[2];
#pragma unroll
      for (int i = 0; i < 4; ++i)
        af[i] = *(const bf16x8*)&Asl[sel][(wm * 64 + i * 16 + l15) * 64 + pu * 8];
#pragma unroll
      for (int j = 0; j < 2; ++j)
        bfr[j] = *(const bf16x8*)&Bsl[sel][(wn * 32 + j * 16 + l15) * 64 + pu * 8];
#pragma unroll
      for (int i = 0; i < 4; ++i)
#pragma unroll
        for (int j = 0; j < 2; ++j)
          acc[i][j] = __builtin_amdgcn_mfma_f32_16x16x32_bf16(af[i], bfr[j], acc[i][j], 0, 0, 0);
    }
    if (t == nk - 1) break;
    __builtin_amdgcn_sched_barrier(0);
    __builtin_amdgcn_s_barrier();        // A
    __builtin_amdgcn_sched_barrier(0);
    if (t + 2 < nk) {
      STAGE((t + 2) << 6, sel);
      asm volatile("s_waitcnt vmcnt(6)" ::: "memory");
    } else {
      asm volatile("s_waitcnt vmcnt(0)" ::: "memory");
    }
    __builtin_amdgcn_sched_barrier(0);
    __builtin_amdgcn_s_barrier();        // B
    __builtin_amdgcn_sched_barrier(0);
  }

  float* P = blockIdx.z ? P1 : P0;
#pragma unroll
  for (int i = 0; i < 4; ++i) {
#pragma unroll
    for (int j = 0; j < 2; ++j) {
      int n = bn + wn * 32 + j * 16 + l15;
#pragma unroll
      for (int r = 0; r < 4; ++r) {
        int m = bm + wm * 64 + i * 16 + quad * 4 + r;
        P[(size_t)m * N + n] = acc[i][j][r];
      }
    }
  }
}

// ---------------- split-K reduce: O = P0 + P1 + bias + res ------------------
__global__ __launch_bounds__(256) void red_kernel(
    const float* P0, const float* __restrict__ P1,
    const float* __restrict__ bias, const float* __restrict__ res,
    float* O, int Ncols) {
  int i = blockIdx.x * 256 + threadIdx.x;
  float4 a = ((const float4*)P0)[i];
  float4 b = ((const float4*)P1)[i];
  float4 r = ((const float4*)res)[i];
  int col = (i * 4) % Ncols;
  float4 bi = *(const float4*)&bias[col];
  float4 o;
  o.x = a.x + b.x + r.x + bi.x;
  o.y = a.y + b.y + r.y + bi.y;
  o.z = a.z + b.z + r.z + bi.z;
  o.w = a.w + b.w + r.w + bi.w;
  ((float4*)O)[i] = o;
}

// ---------------- 8-wave MFMA flash attention, (ws,js)-partitioned ----------
// R12: main loop REVERTED to R10 (double-buffer t&1, barriers A+B, vmcnt(2) —
// measured best at 47.4 µs; R11's single-barrier mod-3 loop regressed to 52.6:
// runtime %3 indexing defeats unroll-by-2 constant folding, both pipes' busy%
// dropped). Epilogue REBUILT for full-line stores: reduce one ws-half at a
// time with ALL 64 d resident (LDSw [4js][64d][33] = 33.8 KB, reused arena);
// 16-lane groups write 128 B contiguous 128-B-aligned = one full cache line.
// (R10/R11 wrote 32/64 B halves of the 128 B line in separate passes -> 2x
// write-allocate amplification, WRITE_SIZE 13.8/12.3 MB vs 6.3 ideal.)
#define LQP 33
__global__ __launch_bounds__(512, 6) void attn_kernel(const u16* __restrict__ qkv,
                                                      const u16* __restrict__ vT,
                                                      u16* __restrict__ out) {
  __shared__ __align__(16) char arena[40960];
  u16* Qsp = (u16*)arena;                 // 64x64 u16 (8 KB)
  u16* Ksp = (u16*)(arena + 8192);        // [2][64x64] u16 (16 KB)
  u16* Vsp = (u16*)(arena + 24576);       // [2][64x64] u16 (16 KB)

  int nwg = gridDim.x * gridDim.y * gridDim.z;
  int bid = (blockIdx.z * gridDim.y + blockIdx.y) * gridDim.x + blockIdx.x;
  int swz = (bid & 7) * (nwg >> 3) + (bid >> 3);
  int bx = swz % gridDim.x;
  int rem = swz / gridDim.x;
  int h = rem % gridDim.y, b = rem / gridDim.y;

  int tid = threadIdx.x;
  int lane = tid & 63, wave = tid >> 6;   // 8 waves
  int ws = wave & 1, js = wave >> 1;      // q-half, j-stripe
  int l15 = lane & 15, quad = lane >> 4;
  int qt = bx * 64;
  size_t base = (size_t)b * SEQ;
  int srow = lane >> 3;                 // 0..7 within an 8-row DMA chunk
  int sux = (lane & 7) ^ (srow & 7);    // XOR-swizzled global 16B col-unit
  int r0 = wave * 8;                    // this wave's staging row base (8 rows)
  const u16* qbase = qkv + (base + qt) * 2304 + h * HD;
  const u16* kbase = qkv + base * 2304 + 768 + h * HD;
  const u16* vbase = vT + ((size_t)(b * HEADS + h) * HD) * SEQ;

  // stage Q + K/V tile 0 (wave w covers rows r0..r0+7 = one 8-row chunk)
  gl_lds16(qbase + (size_t)(r0 + srow) * 2304 + sux * 8, Qsp + r0 * 64);
  gl_lds16(kbase + (size_t)(r0 + srow) * 2304 + sux * 8, Ksp + r0 * 64);
  gl_lds16(vbase + (size_t)(r0 + srow) * SEQ + sux * 8, Vsp + r0 * 64);
  __syncthreads();   // full drain: tile-0 data + Q visible

  int xr = l15 & 7;
  // Q-frags: q-group g (rows ws*32 + g*16 + l15), k-step s (32 k each)
  bf16x8 qf[2][2];
#pragma unroll
  for (int g = 0; g < 2; ++g)
#pragma unroll
    for (int s = 0; s < 2; ++s)
      qf[g][s] = *(const bf16x8*)&Qsp[(ws * 32 + g * 16 + l15) * 64 + ((s * 4 + quad) ^ xr) * 8];

  // prefetch tile 1 into buf 1 (in flight across tile 0's compute)
  gl_lds16(kbase + (size_t)(64 + r0 + srow) * 2304 + sux * 8, Ksp + 4096 + r0 * 64);
  gl_lds16(vbase + (size_t)(r0 + srow) * SEQ + 64 + sux * 8, Vsp + 4096 + r0 * 64);

  // tile-invariant LDS element offsets (stripe js)
  int koff0 = (js * 16 + l15) * 64 + ((quad ^ xr)) * 8;
  int koff1 = (js * 16 + l15) * 64 + (((4 + quad) ^ xr)) * 8;
  int voff[4];
#pragma unroll
  for (int dg = 0; dg < 4; ++dg)
    voff[dg] = (dg * 16 + l15) * 64 + (((2 * js + (quad >> 1)) ^ xr)) * 8 + (quad & 1) * 4;

  f32x4 oT[4][2] = {};   // [dg][g] : O^T tiles (d rows, q cols), js-partial
  f32x4 oT1[2] = {};     // [g] : ones-row accumulators (stripe row-sums of P)
  const short4v ONES = {(short)0x3F80, (short)0x3F80, (short)0x3F80, (short)0x3F80};
  int buf = 0;

  for (int t = 0; t < 32; ++t) {
    const u16* Kb = Ksp + buf * 4096;
    const u16* Vb = Vsp + buf * 4096;

    // QK^T: S^T[j-stripe 16][q-half 32] ; lane: j=16js+quad*4+r, q=ws*32+16g+l15
    f32x4 sT[2] = {};
    __builtin_amdgcn_s_setprio(1);
    {
      bf16x8 ak = *(const bf16x8*)&Kb[koff0];
#pragma unroll
      for (int g = 0; g < 2; ++g)
        sT[g] = __builtin_amdgcn_mfma_f32_16x16x32_bf16(ak, qf[g][0], sT[g], 0, 0, 0);
      bf16x8 ak1 = *(const bf16x8*)&Kb[koff1];
#pragma unroll
      for (int g = 0; g < 2; ++g)
        sT[g] = __builtin_amdgcn_mfma_f32_16x16x32_bf16(ak1, qf[g][1], sT[g], 0, 0, 0);
    }
    __builtin_amdgcn_s_setprio(0);

    // softmax (max-free, Q pre-scaled): p = 2^s ; pack -> x16 B-frags
    short4v pb[2];
#pragma unroll
    for (int g = 0; g < 2; ++g) {
      float p0 = __builtin_amdgcn_exp2f(sT[g][0]);
      float p1 = __builtin_amdgcn_exp2f(sT[g][1]);
      float p2 = __builtin_amdgcn_exp2f(sT[g][2]);
      float p3 = __builtin_amdgcn_exp2f(sT[g][3]);
      union { unsigned u[2]; short4v s; } cv;
      cv.u[0] = pku32(p0, p1);
      cv.u[1] = pku32(p2, p3);
      pb[g] = cv.s;
    }

    // PV: oT[dg][g] += V^T[d-block][stripe] * P^T[stripe][q-group]
    // + ones row: oT1[g] += 1s * P^T  (stripe row-sum -> l partials)
    short4v av[4];
#pragma unroll
    for (int dg = 0; dg < 4; ++dg)
      av[dg] = *(const short4v*)&Vb[voff[dg]];
    __builtin_amdgcn_s_setprio(1);
#pragma unroll
    for (int dg = 0; dg < 4; ++dg)
#pragma unroll
      for (int g = 0; g < 2; ++g)
        oT[dg][g] = __builtin_amdgcn_mfma_f32_16x16x16bf16_1k(av[dg], pb[g], oT[dg][g], 0, 0, 0);
#pragma unroll
    for (int g = 0; g < 2; ++g)
      oT1[g] = __builtin_amdgcn_mfma_f32_16x16x16bf16_1k(ONES, pb[g], oT1[g], 0, 0, 0);
    __builtin_amdgcn_s_setprio(0);

    __builtin_amdgcn_sched_barrier(0);
    __builtin_amdgcn_s_barrier();          // A: all reads of buf done
    __builtin_amdgcn_sched_barrier(0);
    if (t < 30) {  // prefetch tile t+2 into the buffer just freed
      size_t kt2 = (size_t)(t + 2) * 64;
      u16* Kd = Ksp + buf * 4096;
      u16* Vd = Vsp + buf * 4096;
      gl_lds16(kbase + (kt2 + r0 + srow) * 2304 + sux * 8, Kd + r0 * 64);
      gl_lds16(vbase + (size_t)(r0 + srow) * SEQ + kt2 + sux * 8, Vd + r0 * 64);
      asm volatile("s_waitcnt vmcnt(2)" ::: "memory");  // retire t+1's 2 loads
    } else {
      asm volatile("s_waitcnt vmcnt(0)" ::: "memory");
    }
    __builtin_amdgcn_sched_barrier(0);
    __builtin_amdgcn_s_barrier();          // B: t+1 data visible to all waves
    __builtin_amdgcn_sched_barrier(0);
    buf ^= 1;
  }

  // ---- epilogue: reduce js-partial O^T + l, one ws-half per pass ----
  // (t=31's barriers guarantee all K/V reads done -> arena reusable)
  float* LDSw = (float*)arena;             // [4 js][64 d][LQP] f32 (33.8 KB)
  float* lsd  = (float*)(arena + 33792);   // [2 ws][4 js][32 q] f32 (1 KB)
  if (lane < 16) {
#pragma unroll
    for (int g = 0; g < 2; ++g)
      lsd[(ws * 4 + js) * 32 + g * 16 + lane] = oT1[g][0];
  }
  // read map: qq = q-row within half (16 lanes each), lane16*4 = d base ->
  // 16 lanes write 128 B contiguous, 128-B aligned = one full line.
  int qq = tid >> 4, lane16 = tid & 15;
#pragma unroll
  for (int p = 0; p < 2; ++p) {
    __syncthreads();  // p=0: lsd visible; p=1: prev pass reads done
    if (ws == p) {    // write phase: this ws-half's waves deposit all 64 d
#pragma unroll
      for (int dg = 0; dg < 4; ++dg)
#pragma unroll
        for (int g = 0; g < 2; ++g)
#pragma unroll
          for (int r = 0; r < 4; ++r)
            LDSw[(js * 64 + dg * 16 + quad * 4 + r) * LQP + g * 16 + l15] = oT[dg][g][r];
    }
    __syncthreads();
    float L = lsd[(p * 4 + 0) * 32 + qq] + lsd[(p * 4 + 1) * 32 + qq] +
              lsd[(p * 4 + 2) * 32 + qq] + lsd[(p * 4 + 3) * 32 + qq];
    float linv = 1.0f / L;
    float sv[4];
#pragma unroll
    for (int i = 0; i < 4; ++i) {
      int dloc = lane16 * 4 + i;
      float a = LDSw[(0 * 64 + dloc) * LQP + qq] + LDSw[(1 * 64 + dloc) * LQP + qq] +
                LDSw[(2 * 64 + dloc) * LQP + qq] + LDSw[(3 * 64 + dloc) * LQP + qq];
      sv[i] = a * linv;
    }
    size_t addr = (base + qt + p * 32 + qq) * DIM + h * HD + lane16 * 4;
    uint2 pk;
    pk.x = pku32(sv[0], sv[1]);
    pk.y = pku32(sv[2], sv[3]);
    *(uint2*)&out[addr] = pk;
  }
}

extern "C" void kernel_launch(void* const* d_in, const int* in_sizes, int n_in,
                              void* d_out, int out_size, void* d_ws, size_t ws_size,
                              hipStream_t stream) {
  const float* x     = (const float*)d_in[0];
  const float* ln1w  = (const float*)d_in[1];
  const float* ln1b  = (const float*)d_in[2];
  const float* qkvw  = (const float*)d_in[3];
  const float* qkvbi = (const float*)d_in[4];
  const float* projw = (const float*)d_in[5];
  const float* projb = (const float*)d_in[6];
  const float* ln2w  = (const float*)d_in[7];
  const float* ln2b  = (const float*)d_in[8];
  const float* l1w   = (const float*)d_in[9];
  const float* l1b   = (const float*)d_in[10];
  const float* l2w   = (const float*)d_in[11];
  const float* l2b   = (const float*)d_in[12];
  float* out = (float*)d_out;

  char* w = (char*)d_ws;
  u16*   h     = (u16*)w;   w += (size_t)NTOK * DIM * 2;          // 6.3 MB
  u16*   qkvB  = (u16*)w;                                         // 18.9 MB (union)
  u16*   mid   = (u16*)w;   w += (size_t)NTOK * 3072 * 2;         // 25.2 MB union
  u16*   attnb = (u16*)w;   w += (size_t)NTOK * DIM * 2;          // 6.3 MB
  float* x2    = (float*)w; w += (size_t)NTOK * DIM * 4;          // 12.6 MB
  u16*   vTb   = (u16*)w;   w += (size_t)NTOK * DIM * 2;          // 6.3 MB
  u16*   qkvwt = (u16*)w;   w += (size_t)DIM * 2304 * 2;
  u16*   projwt= (u16*)w;   w += (size_t)DIM * DIM * 2;
  u16*   l1wt  = (u16*)w;   w += (size_t)DIM * 3072 * 2;
  u16*   l2wt  = (u16*)w;   w += (size_t)3072 * DIM * 2;
  float* Pbuf  = (float*)w; w += (size_t)NTOK * DIM * 4;          // 12.6 MB (split-K P1)

  wcvt_all<<<6912, 256, 0, stream>>>(qkvw, projw, l1w, l2w,
                                     qkvwt, projwt, l1wt, l2wt);

  ln_kernel<<<NTOK, 256, 0, stream>>>(x, ln1w, ln1b, h);
  bgemm_kernel<<<dim3(2304 / 128, NTOK / 128), 256, 0, stream>>>(
      h, qkvwt, qkvbi, qkvB, NTOK, 2304, DIM, 0, 1);
  vtr_kernel<<<dim3(768 / 32, SEQ / 32, 2), 256, 0, stream>>>(qkvB, vTb);
  attn_kernel<<<dim3(SEQ / 64, HEADS, 2), 512, 0, stream>>>(qkvB, vTb, attnb);

  // proj: split-K x2 -> x2 + Pbuf; fused reduce(+bias+x residual) + LN2
  bgemm_splitk<<<dim3(DIM / 64, NTOK / 128, 2), 256, 0, stream>>>(
      attnb, projwt, x2, Pbuf, NTOK, DIM, DIM);
  redln_kernel<<<NTOK, 256, 0, stream>>>(x2, Pbuf, projb, x, x2, ln2w, ln2b, h);

  bgemm_kernel<<<dim3(3072 / 128, NTOK / 128), 256, 0, stream>>>(
      h, l1wt, l1b, mid, NTOK, 3072, DIM, 1, 0);

  // lin2: split-K x2 -> out + Pbuf; reduce adds bias + x2 residual
  bgemm_splitk<<<dim3(DIM / 64, NTOK / 128, 2), 256, 0, stream>>>(
      mid, l2wt, out, Pbuf, NTOK, DIM, 3072);
  red_kernel<<<NTOK * DIM / 1024, 256, 0, stream>>>(out, Pbuf, l2b, x2, out, DIM);
}

// Round 13
// 270.756 us; speedup vs baseline: 1.0240x; 1.0066x over previous
//
#include <hip/hip_runtime.h>
#include <hip/hip_bf16.h>
#include <math.h>

#define DIM 768
#define NTOK 4096   // B*N = 2*2048
#define SEQ 2048
#define HEADS 12
#define HD 64

using bf16x8 = __attribute__((ext_vector_type(8))) __bf16;
using bf16x4 = __attribute__((ext_vector_type(4))) __bf16;
using short4v = __attribute__((ext_vector_type(4))) short;
using f32x4  = __attribute__((ext_vector_type(4))) float;
typedef unsigned short u16;

#define KEXPF 0.18033688011112042f  // log2(e)/8

__device__ inline u16 f2bf(float f) {
  union { float f; unsigned u; } v; v.f = f;
  unsigned r = v.u + 0x7fffu + ((v.u >> 16) & 1u);  // RNE
  return (u16)(r >> 16);
}

// packed f32x2 -> bf16x2 (v_cvt_pk_bf16_f32)
__device__ inline void pk2bf(float a, float b, u16* o0, u16* o1) {
  union { __hip_bfloat162 h; u16 u[2]; } cv;
  cv.h = __float22bfloat162_rn(make_float2(a, b));
  *o0 = cv.u[0];
  *o1 = cv.u[1];
}

// packed f32x2 -> one u32 of 2 bf16 (lo = a, hi = b)
__device__ inline unsigned pku32(float a, float b) {
  union { __hip_bfloat162 h; unsigned u; } cv;
  cv.h = __float22bfloat162_rn(make_float2(a, b));
  return cv.u;
}

// GELU, sigmoid form: x*sigmoid(1.5957691x + 0.0713548x^3); |err| < ~3e-3.
__device__ inline float gelu_t(float x) {
  float z = x * (1.5957691216f + 0.0713548162f * x * x);
  return x / (1.0f + __expf(-z));
}

// async global->LDS DMA, 16 B per lane; LDS dest = wave-uniform base + lane*16
__device__ inline void gl_lds16(const u16* g, u16* l) {
  __builtin_amdgcn_global_load_lds(
      (const __attribute__((address_space(1))) unsigned int*)g,
      (__attribute__((address_space(3))) unsigned int*)l, 16, 0, 0);
}

// ---------------- LayerNorm: fp32 in -> bf16 out ----------------
__global__ __launch_bounds__(256) void ln_kernel(const float* __restrict__ x,
                                                 const float* __restrict__ w,
                                                 const float* __restrict__ b,
                                                 u16* __restrict__ y) {
  int row = blockIdx.x;
  int t = threadIdx.x;
  const float* xr = x + (size_t)row * DIM;
  float v0 = xr[t], v1 = xr[t + 256], v2 = xr[t + 512];
  float s = v0 + v1 + v2;
  float q = v0 * v0 + v1 * v1 + v2 * v2;
  for (int o = 32; o > 0; o >>= 1) {
    s += __shfl_down(s, o, 64);
    q += __shfl_down(q, o, 64);
  }
  __shared__ float ws_[4], wq_[4], mb[2];
  int wid = t >> 6;
  if ((t & 63) == 0) { ws_[wid] = s; wq_[wid] = q; }
  __syncthreads();
  if (t == 0) {
    float S = ws_[0] + ws_[1] + ws_[2] + ws_[3];
    float Q = wq_[0] + wq_[1] + wq_[2] + wq_[3];
    float mean = S * (1.0f / DIM);
    float var = Q * (1.0f / DIM) - mean * mean;
    mb[0] = mean;
    mb[1] = rsqrtf(var + 1e-5f);
  }
  __syncthreads();
  float mean = mb[0], rstd = mb[1];
  u16* yr = y + (size_t)row * DIM;
  yr[t]       = f2bf((v0 - mean) * rstd * w[t]       + b[t]);
  yr[t + 256] = f2bf((v1 - mean) * rstd * w[t + 256] + b[t + 256]);
  yr[t + 512] = f2bf((v2 - mean) * rstd * w[t + 512] + b[t + 512]);
}

// -------- fused split-K reduce + residual + bias -> x2 (fp32) + LN -> h (bf16)
__global__ __launch_bounds__(256) void redln_kernel(
    const float* __restrict__ P0, const float* __restrict__ P1,
    const float* __restrict__ bias, const float* __restrict__ res,
    float* __restrict__ x2, const float* __restrict__ lnw,
    const float* __restrict__ lnb, u16* __restrict__ y) {
  int row = blockIdx.x;
  int t = threadIdx.x;
  size_t off = (size_t)row * DIM;
  float v[3];
#pragma unroll
  for (int k = 0; k < 3; ++k) {
    int c = t + k * 256;
    v[k] = P0[off + c] + P1[off + c] + bias[c] + res[off + c];
    x2[off + c] = v[k];
  }
  float s = v[0] + v[1] + v[2];
  float q = v[0] * v[0] + v[1] * v[1] + v[2] * v[2];
  for (int o = 32; o > 0; o >>= 1) {
    s += __shfl_down(s, o, 64);
    q += __shfl_down(q, o, 64);
  }
  __shared__ float ws_[4], wq_[4], mb[2];
  int wid = t >> 6;
  if ((t & 63) == 0) { ws_[wid] = s; wq_[wid] = q; }
  __syncthreads();
  if (t == 0) {
    float S = ws_[0] + ws_[1] + ws_[2] + ws_[3];
    float Q = wq_[0] + wq_[1] + wq_[2] + wq_[3];
    float mean = S * (1.0f / DIM);
    float var = Q * (1.0f / DIM) - mean * mean;
    mb[0] = mean;
    mb[1] = rsqrtf(var + 1e-5f);
  }
  __syncthreads();
  float mean = mb[0], rstd = mb[1];
#pragma unroll
  for (int k = 0; k < 3; ++k) {
    int c = t + k * 256;
    y[off + c] = f2bf((v[k] - mean) * rstd * lnw[c] + lnb[c]);
  }
}

// ---------------- all 4 weight converts in one launch (dims compile-time) ----
__global__ __launch_bounds__(256) void wcvt_all(
    const float* __restrict__ W0, const float* __restrict__ W1,
    const float* __restrict__ W2, const float* __restrict__ W3,
    u16* __restrict__ T0, u16* __restrict__ T1,
    u16* __restrict__ T2, u16* __restrict__ T3) {
  int id = blockIdx.x;
  const float* W; u16* Wt; int K, N, local;
  if (id < 1728)      { W = W0; Wt = T0; K = 768;  N = 2304; local = id; }
  else if (id < 2304) { W = W1; Wt = T1; K = 768;  N = 768;  local = id - 1728; }
  else if (id < 4608) { W = W2; Wt = T2; K = 768;  N = 3072; local = id - 2304; }
  else                { W = W3; Wt = T3; K = 3072; N = 768;  local = id - 4608; }
  int ntiles = N / 32;
  int n0 = (local % ntiles) * 32, k0 = (local / ntiles) * 32;
  __shared__ float tile[32][33];
  int tid = threadIdx.x;
  int c = tid & 31, r8 = tid >> 5;
#pragma unroll
  for (int p = 0; p < 4; ++p) {
    int k = r8 + p * 8;
    tile[k][c] = W[(size_t)(k0 + k) * N + n0 + c];
  }
  __syncthreads();
#pragma unroll
  for (int p = 0; p < 4; ++p) {
    int n = r8 + p * 8;
    Wt[(size_t)(n0 + n) * K + k0 + c] = f2bf(tile[c][n]);
  }
}

// ---------------- bf16 MFMA GEMM (full-K): Cb = act(A * Bt^T + bias) --------
// R8 config (kept): BK=32 triple-buffer, 48 KB LDS, counted vmcnt, prefetch
// distance 2. XCD-aware bijective swizzle.
// R13: vfuse — for the qkv GEMM, V-tiles (bn >= 1536, tile-aligned) are NOT
// written to Cb; instead the 128x128 output is bounced through LDS (stride
// 136 u16, uint2 deposits) and streamed out TRANSPOSED directly into the
// vT[b][v][j] layout (16 B chunks, 256 B contiguous per row-segment).
// This deletes the standalone vtr kernel and its 12.6 MB HBM round trip.
__global__ __launch_bounds__(256) void bgemm_kernel(
    const u16* __restrict__ A, const u16* __restrict__ Bt,
    const float* __restrict__ bias, u16* __restrict__ Cb,
    int M, int N, int K, int act, int scaleq,
    u16* __restrict__ vTout, int vfuse) {
  __shared__ __align__(16) u16 ABar[3 * 128 * 32 * 2];  // 48 KB arena
  u16* AslF = ABar;                 // [3][128*32]
  u16* BslF = ABar + 3 * 128 * 32;  // [3][128*32]
  int nwg = gridDim.x * gridDim.y;
  int bid = blockIdx.y * gridDim.x + blockIdx.x;
  int swz = (bid & 7) * (nwg >> 3) + (bid >> 3);
  int bx = swz % gridDim.x, by = swz / gridDim.x;
  int tid = threadIdx.x;
  int lane = tid & 63, wave = tid >> 6;
  int wm = wave >> 1, wn = wave & 1;
  int bm = by * 128, bn = bx * 128;
  int l15 = lane & 15, quad = lane >> 4;
  int srow4 = lane >> 2;                        // 0..15: row within 16-row chunk
  int gux = (lane & 3) ^ ((srow4 + (srow4 >> 2)) & 3);  // swizzled global unit

  f32x4 acc[4][4] = {};
  const u16* Ap = A + (size_t)(bm + wave * 16 + srow4) * K + gux * 8;
  const u16* Bp = Bt + (size_t)(bn + wave * 16 + srow4) * K + gux * 8;
  int fx = (l15 + (l15 >> 2)) & 3;              // f(read row)
  int nk = K >> 5;

  auto STAGE = [&](int k0, int sel) {
#pragma unroll
    for (int p = 0; p < 2; ++p)
      gl_lds16(Ap + (size_t)(p * 64) * K + k0, AslF + sel * 4096 + (wave * 16 + p * 64) * 32);
#pragma unroll
    for (int p = 0; p < 2; ++p)
      gl_lds16(Bp + (size_t)(p * 64) * K + k0, BslF + sel * 4096 + (wave * 16 + p * 64) * 32);
  };

  STAGE(0, 0);
  STAGE(32, 1);
  STAGE(64, 2);
  asm volatile("s_waitcnt vmcnt(8)" ::: "memory");  // tile 0's 4 loads done
  __builtin_amdgcn_s_barrier();

  int sel = 0;
  for (int t = 0; t < nk; ++t) {
    bf16x8 af[4], bfr[4];
#pragma unroll
    for (int i = 0; i < 4; ++i) {
      af[i]  = *(const bf16x8*)&AslF[sel * 4096 + (wm * 64 + i * 16 + l15) * 32 + (quad ^ fx) * 8];
      bfr[i] = *(const bf16x8*)&BslF[sel * 4096 + (wn * 64 + i * 16 + l15) * 32 + (quad ^ fx) * 8];
    }
#pragma unroll
    for (int i = 0; i < 4; ++i)
#pragma unroll
      for (int j = 0; j < 4; ++j)
        acc[i][j] = __builtin_amdgcn_mfma_f32_16x16x32_bf16(af[i], bfr[j], acc[i][j], 0, 0, 0);
    if (t == nk - 1) break;
    __builtin_amdgcn_sched_barrier(0);
    __builtin_amdgcn_s_barrier();        // A: all reads of sel done
    __builtin_amdgcn_sched_barrier(0);
    if (t + 3 < nk) {
      STAGE((t + 3) << 5, sel);
      asm volatile("s_waitcnt vmcnt(8)" ::: "memory");  // retire t+1's 4 loads
    } else if (t + 2 < nk) {
      asm volatile("s_waitcnt vmcnt(4)" ::: "memory");  // retire t+1's 4 loads
    } else {
      asm volatile("s_waitcnt vmcnt(0)" ::: "memory");
    }
    __builtin_amdgcn_sched_barrier(0);
    __builtin_amdgcn_s_barrier();        // B: t+1 data visible
    __builtin_amdgcn_sched_barrier(0);
    sel = (sel == 2) ? 0 : sel + 1;
  }

  if (!(vfuse && bn >= 1536)) {
    // normal epilogue: bias (+gelu) -> bf16 -> coalesced Cb stores
#pragma unroll
    for (int i = 0; i < 4; ++i) {
#pragma unroll
      for (int j = 0; j < 4; ++j) {
        int n = bn + wn * 64 + j * 16 + l15;
        float bv = bias[n];
        float cs = (scaleq && n < 768) ? KEXPF : 1.0f;
        float val[4];
#pragma unroll
        for (int r = 0; r < 4; ++r) {
          float v = (acc[i][j][r] + bv) * cs;
          val[r] = act ? gelu_t(v) : v;
        }
        u16 c0, c1, c2, c3;
        pk2bf(val[0], val[1], &c0, &c1);
        pk2bf(val[2], val[3], &c2, &c3);
        size_t mbase = (size_t)(bm + wm * 64 + i * 16 + quad * 4) * N + n;
        Cb[mbase]         = c0;
        Cb[mbase + N]     = c1;
        Cb[mbase + 2 * N] = c2;
        Cb[mbase + 3 * N] = c3;
      }
    }
  } else {
    // fused V-transpose epilogue: bounce the tile through LDS, write vT
    __syncthreads();   // all k-loop LDS reads (every wave) done before reuse
    u16* Lt = ABar;    // [128 n][136 m] u16 (34.8 KB)
#pragma unroll
    for (int i = 0; i < 4; ++i)
#pragma unroll
      for (int j = 0; j < 4; ++j) {
        int n_local = wn * 64 + j * 16 + l15;
        float bv = bias[bn + n_local];
        uint2 pk;
        pk.x = pku32(acc[i][j][0] + bv, acc[i][j][1] + bv);
        pk.y = pku32(acc[i][j][2] + bv, acc[i][j][3] + bv);
        int m0 = wm * 64 + i * 16 + quad * 4;
        *(uint2*)&Lt[n_local * 136 + m0] = pk;   // 4 consecutive m as bf16
      }
    __syncthreads();
    // readout: thread -> (n_local = tid>>1, half = tid&1); 64 u16 = 128 B
    // contiguous in vT row (b*768 + v)*SEQ + j0 + half*64
    int n_local = tid >> 1, half = tid & 1;
    int bb = bm >> 11, j0 = bm & 2047;
    u16* dst = vTout + ((size_t)(bb * 768 + (bn - 1536) + n_local)) * SEQ + j0 + half * 64;
    const u16* src = &Lt[n_local * 136 + half * 64];
#pragma unroll
    for (int k = 0; k < 8; ++k)
      *(uint4*)(dst + k * 8) = *(const uint4*)(src + k * 8);
  }
}

// ---------------- bf16 MFMA GEMM, split-K x2, 128x64 tile, BK=64 ------------
// R5 structure kept: counted-vmcnt double-buffer, 48 KB LDS (3 blocks/CU).
__global__ __launch_bounds__(256) void bgemm_splitk(
    const u16* __restrict__ A, const u16* __restrict__ Bt,
    float* __restrict__ P0, float* __restrict__ P1,
    int M, int N, int K) {
  __shared__ __align__(16) u16 Asl[2][128 * 64];
  __shared__ __align__(16) u16 Bsl[2][64 * 64];
  int nwg = gridDim.x * gridDim.y;
  int bid = blockIdx.y * gridDim.x + blockIdx.x;
  int swz = (bid & 7) * (nwg >> 3) + (bid >> 3);
  int bx = swz % gridDim.x, by = swz / gridDim.x;
  int tid = threadIdx.x;
  int lane = tid & 63, wave = tid >> 6;
  int wm = wave >> 1, wn = wave & 1;
  int bm = by * 128, bn = bx * 64;
  int l15 = lane & 15, quad = lane >> 4;
  int sm8 = tid >> 3;
  int kgx = (tid & 7) ^ (sm8 & 7);
  int half = K >> 1;
  int kbeg = blockIdx.z * half;

  f32x4 acc[4][2] = {};
  const u16* Ap = A + (size_t)(bm + sm8) * K + kbeg + kgx * 8;
  const u16* Bp = Bt + (size_t)(bn + sm8) * K + kbeg + kgx * 8;
  int xr = l15 & 7;
  int nk = half >> 6;

  auto STAGE = [&](int k0, int sel) {
#pragma unroll
    for (int p = 0; p < 4; ++p)
      gl_lds16(Ap + (size_t)(p * 32) * K + k0, &Asl[sel][(wave * 8 + p * 32) * 64]);
#pragma unroll
    for (int p = 0; p < 2; ++p)
      gl_lds16(Bp + (size_t)(p * 32) * K + k0, &Bsl[sel][(wave * 8 + p * 32) * 64]);
  };

  STAGE(0, 0);
  if (nk > 1) STAGE(64, 1);
  asm volatile("s_waitcnt vmcnt(6)" ::: "memory");
  __builtin_amdgcn_s_barrier();

  for (int t = 0; t < nk; ++t) {
    int sel = t & 1;
#pragma unroll
    for (int ks = 0; ks < 2; ++ks) {
      int pu = ((ks << 2) + quad) ^ xr;
      bf16x8 af[4], bfr[2];
#pragma unroll
      for (int i = 0; i < 4; ++i)
        af[i] = *(const bf16x8*)&Asl[sel][(wm * 64 + i * 16 + l15) * 64 + pu * 8];
#pragma unroll
      for (int j = 0; j < 2; ++j)
        bfr[j] = *(const bf16x8*)&Bsl[sel][(wn * 32 + j * 16 + l15) * 64 + pu * 8];
#pragma unroll
      for (int i = 0; i < 4; ++i)
#pragma unroll
        for (int j = 0; j < 2; ++j)
          acc[i][j] = __builtin_amdgcn_mfma_f32_16x16x32_bf16(af[i], bfr[j], acc[i][j], 0, 0, 0);
    }
    if (t == nk - 1) break;
    __builtin_amdgcn_sched_barrier(0);
    __builtin_amdgcn_s_barrier();        // A
    __builtin_amdgcn_sched_barrier(0);
    if (t + 2 < nk) {
      STAGE((t + 2) << 6, sel);
      asm volatile("s_waitcnt vmcnt(6)" ::: "memory");
    } else {
      asm volatile("s_waitcnt vmcnt(0)" ::: "memory");
    }
    __builtin_amdgcn_sched_barrier(0);
    __builtin_amdgcn_s_barrier();        // B
    __builtin_amdgcn_sched_barrier(0);
  }

  float* P = blockIdx.z ? P1 : P0;
#pragma unroll
  for (int i = 0; i < 4; ++i) {
#pragma unroll
    for (int j = 0; j < 2; ++j) {
      int n = bn + wn * 32 + j * 16 + l15;
#pragma unroll
      for (int r = 0; r < 4; ++r) {
        int m = bm + wm * 64 + i * 16 + quad * 4 + r;
        P[(size_t)m * N + n] = acc[i][j][r];
      }
    }
  }
}

// ---------------- split-K reduce: O = P0 + P1 + bias + res ------------------
__global__ __launch_bounds__(256) void red_kernel(
    const float* P0, const float* __restrict__ P1,
    const float* __restrict__ bias, const float* __restrict__ res,
    float* O, int Ncols) {
  int i = blockIdx.x * 256 + threadIdx.x;
  float4 a = ((const float4*)P0)[i];
  float4 b = ((const float4*)P1)[i];
  float4 r = ((const float4*)res)[i];
  int col = (i * 4) % Ncols;
  float4 bi = *(const float4*)&bias[col];
  float4 o;
  o.x = a.x + b.x + r.x + bi.x;
  o.y = a.y + b.y + r.y + bi.y;
  o.z = a.z + b.z + r.z + bi.z;
  o.w = a.w + b.w + r.w + bi.w;
  ((float4*)O)[i] = o;
}

// ---------------- 8-wave MFMA flash attention, (ws,js)-partitioned ----------
// R12 config (kept): double-buffer t&1 main loop, barriers A+B, vmcnt(2),
// ones-MFMA lsum, pre-scaled Q, XCD swizzle, full-line epilogue.
#define LQP 33
__global__ __launch_bounds__(512, 6) void attn_kernel(const u16* __restrict__ qkv,
                                                      const u16* __restrict__ vT,
                                                      u16* __restrict__ out) {
  __shared__ __align__(16) char arena[40960];
  u16* Qsp = (u16*)arena;                 // 64x64 u16 (8 KB)
  u16* Ksp = (u16*)(arena + 8192);        // [2][64x64] u16 (16 KB)
  u16* Vsp = (u16*)(arena + 24576);       // [2][64x64] u16 (16 KB)

  int nwg = gridDim.x * gridDim.y * gridDim.z;
  int bid = (blockIdx.z * gridDim.y + blockIdx.y) * gridDim.x + blockIdx.x;
  int swz = (bid & 7) * (nwg >> 3) + (bid >> 3);
  int bx = swz % gridDim.x;
  int rem = swz / gridDim.x;
  int h = rem % gridDim.y, b = rem / gridDim.y;

  int tid = threadIdx.x;
  int lane = tid & 63, wave = tid >> 6;   // 8 waves
  int ws = wave & 1, js = wave >> 1;      // q-half, j-stripe
  int l15 = lane & 15, quad = lane >> 4;
  int qt = bx * 64;
  size_t base = (size_t)b * SEQ;
  int srow = lane >> 3;                 // 0..7 within an 8-row DMA chunk
  int sux = (lane & 7) ^ (srow & 7);    // XOR-swizzled global 16B col-unit
  int r0 = wave * 8;                    // this wave's staging row base (8 rows)
  const u16* qbase = qkv + (base + qt) * 2304 + h * HD;
  const u16* kbase = qkv + base * 2304 + 768 + h * HD;
  const u16* vbase = vT + ((size_t)(b * HEADS + h) * HD) * SEQ;

  // stage Q + K/V tile 0 (wave w covers rows r0..r0+7 = one 8-row chunk)
  gl_lds16(qbase + (size_t)(r0 + srow) * 2304 + sux * 8, Qsp + r0 * 64);
  gl_lds16(kbase + (size_t)(r0 + srow) * 2304 + sux * 8, Ksp + r0 * 64);
  gl_lds16(vbase + (size_t)(r0 + srow) * SEQ + sux * 8, Vsp + r0 * 64);
  __syncthreads();   // full drain: tile-0 data + Q visible

  int xr = l15 & 7;
  // Q-frags: q-group g (rows ws*32 + g*16 + l15), k-step s (32 k each)
  bf16x8 qf[2][2];
#pragma unroll
  for (int g = 0; g < 2; ++g)
#pragma unroll
    for (int s = 0; s < 2; ++s)
      qf[g][s] = *(const bf16x8*)&Qsp[(ws * 32 + g * 16 + l15) * 64 + ((s * 4 + quad) ^ xr) * 8];

  // prefetch tile 1 into buf 1 (in flight across tile 0's compute)
  gl_lds16(kbase + (size_t)(64 + r0 + srow) * 2304 + sux * 8, Ksp + 4096 + r0 * 64);
  gl_lds16(vbase + (size_t)(r0 + srow) * SEQ + 64 + sux * 8, Vsp + 4096 + r0 * 64);

  // tile-invariant LDS element offsets (stripe js)
  int koff0 = (js * 16 + l15) * 64 + ((quad ^ xr)) * 8;
  int koff1 = (js * 16 + l15) * 64 + (((4 + quad) ^ xr)) * 8;
  int voff[4];
#pragma unroll
  for (int dg = 0; dg < 4; ++dg)
    voff[dg] = (dg * 16 + l15) * 64 + (((2 * js + (quad >> 1)) ^ xr)) * 8 + (quad & 1) * 4;

  f32x4 oT[4][2] = {};   // [dg][g] : O^T tiles (d rows, q cols), js-partial
  f32x4 oT1[2] = {};     // [g] : ones-row accumulators (stripe row-sums of P)
  const short4v ONES = {(short)0x3F80, (short)0x3F80, (short)0x3F80, (short)0x3F80};
  int buf = 0;

  for (int t = 0; t < 32; ++t) {
    const u16* Kb = Ksp + buf * 4096;
    const u16* Vb = Vsp + buf * 4096;

    // QK^T: S^T[j-stripe 16][q-half 32] ; lane: j=16js+quad*4+r, q=ws*32+16g+l15
    f32x4 sT[2] = {};
    __builtin_amdgcn_s_setprio(1);
    {
      bf16x8 ak = *(const bf16x8*)&Kb[koff0];
#pragma unroll
      for (int g = 0; g < 2; ++g)
        sT[g] = __builtin_amdgcn_mfma_f32_16x16x32_bf16(ak, qf[g][0], sT[g], 0, 0, 0);
      bf16x8 ak1 = *(const bf16x8*)&Kb[koff1];
#pragma unroll
      for (int g = 0; g < 2; ++g)
        sT[g] = __builtin_amdgcn_mfma_f32_16x16x32_bf16(ak1, qf[g][1], sT[g], 0, 0, 0);
    }
    __builtin_amdgcn_s_setprio(0);

    // softmax (max-free, Q pre-scaled): p = 2^s ; pack -> x16 B-frags
    short4v pb[2];
#pragma unroll
    for (int g = 0; g < 2; ++g) {
      float p0 = __builtin_amdgcn_exp2f(sT[g][0]);
      float p1 = __builtin_amdgcn_exp2f(sT[g][1]);
      float p2 = __builtin_amdgcn_exp2f(sT[g][2]);
      float p3 = __builtin_amdgcn_exp2f(sT[g][3]);
      union { unsigned u[2]; short4v s; } cv;
      cv.u[0] = pku32(p0, p1);
      cv.u[1] = pku32(p2, p3);
      pb[g] = cv.s;
    }

    // PV: oT[dg][g] += V^T[d-block][stripe] * P^T[stripe][q-group]
    // + ones row: oT1[g] += 1s * P^T  (stripe row-sum -> l partials)
    short4v av[4];
#pragma unroll
    for (int dg = 0; dg < 4; ++dg)
      av[dg] = *(const short4v*)&Vb[voff[dg]];
    __builtin_amdgcn_s_setprio(1);
#pragma unroll
    for (int dg = 0; dg < 4; ++dg)
#pragma unroll
      for (int g = 0; g < 2; ++g)
        oT[dg][g] = __builtin_amdgcn_mfma_f32_16x16x16bf16_1k(av[dg], pb[g], oT[dg][g], 0, 0, 0);
#pragma unroll
    for (int g = 0; g < 2; ++g)
      oT1[g] = __builtin_amdgcn_mfma_f32_16x16x16bf16_1k(ONES, pb[g], oT1[g], 0, 0, 0);
    __builtin_amdgcn_s_setprio(0);

    __builtin_amdgcn_sched_barrier(0);
    __builtin_amdgcn_s_barrier();          // A: all reads of buf done
    __builtin_amdgcn_sched_barrier(0);
    if (t < 30) {  // prefetch tile t+2 into the buffer just freed
      size_t kt2 = (size_t)(t + 2) * 64;
      u16* Kd = Ksp + buf * 4096;
      u16* Vd = Vsp + buf * 4096;
      gl_lds16(kbase + (kt2 + r0 + srow) * 2304 + sux * 8, Kd + r0 * 64);
      gl_lds16(vbase + (size_t)(r0 + srow) * SEQ + kt2 + sux * 8, Vd + r0 * 64);
      asm volatile("s_waitcnt vmcnt(2)" ::: "memory");  // retire t+1's 2 loads
    } else {
      asm volatile("s_waitcnt vmcnt(0)" ::: "memory");
    }
    __builtin_amdgcn_sched_barrier(0);
    __builtin_amdgcn_s_barrier();          // B: t+1 data visible to all waves
    __builtin_amdgcn_sched_barrier(0);
    buf ^= 1;
  }

  // ---- epilogue: reduce js-partial O^T + l, one ws-half per pass ----
  float* LDSw = (float*)arena;             // [4 js][64 d][LQP] f32 (33.8 KB)
  float* lsd  = (float*)(arena + 33792);   // [2 ws][4 js][32 q] f32 (1 KB)
  if (lane < 16) {
#pragma unroll
    for (int g = 0; g < 2; ++g)
      lsd[(ws * 4 + js) * 32 + g * 16 + lane] = oT1[g][0];
  }
  int qq = tid >> 4, lane16 = tid & 15;
#pragma unroll
  for (int p = 0; p < 2; ++p) {
    __syncthreads();  // p=0: lsd visible; p=1: prev pass reads done
    if (ws == p) {    // write phase: this ws-half's waves deposit all 64 d
#pragma unroll
      for (int dg = 0; dg < 4; ++dg)
#pragma unroll
        for (int g = 0; g < 2; ++g)
#pragma unroll
          for (int r = 0; r < 4; ++r)
            LDSw[(js * 64 + dg * 16 + quad * 4 + r) * LQP + g * 16 + l15] = oT[dg][g][r];
    }
    __syncthreads();
    float L = lsd[(p * 4 + 0) * 32 + qq] + lsd[(p * 4 + 1) * 32 + qq] +
              lsd[(p * 4 + 2) * 32 + qq] + lsd[(p * 4 + 3) * 32 + qq];
    float linv = 1.0f / L;
    float sv[4];
#pragma unroll
    for (int i = 0; i < 4; ++i) {
      int dloc = lane16 * 4 + i;
      float a = LDSw[(0 * 64 + dloc) * LQP + qq] + LDSw[(1 * 64 + dloc) * LQP + qq] +
                LDSw[(2 * 64 + dloc) * LQP + qq] + LDSw[(3 * 64 + dloc) * LQP + qq];
      sv[i] = a * linv;
    }
    size_t addr = (base + qt + p * 32 + qq) * DIM + h * HD + lane16 * 4;
    uint2 pk;
    pk.x = pku32(sv[0], sv[1]);
    pk.y = pku32(sv[2], sv[3]);
    *(uint2*)&out[addr] = pk;
  }
}

extern "C" void kernel_launch(void* const* d_in, const int* in_sizes, int n_in,
                              void* d_out, int out_size, void* d_ws, size_t ws_size,
                              hipStream_t stream) {
  const float* x     = (const float*)d_in[0];
  const float* ln1w  = (const float*)d_in[1];
  const float* ln1b  = (const float*)d_in[2];
  const float* qkvw  = (const float*)d_in[3];
  const float* qkvbi = (const float*)d_in[4];
  const float* projw = (const float*)d_in[5];
  const float* projb = (const float*)d_in[6];
  const float* ln2w  = (const float*)d_in[7];
  const float* ln2b  = (const float*)d_in[8];
  const float* l1w   = (const float*)d_in[9];
  const float* l1b   = (const float*)d_in[10];
  const float* l2w   = (const float*)d_in[11];
  const float* l2b   = (const float*)d_in[12];
  float* out = (float*)d_out;

  char* w = (char*)d_ws;
  u16*   h     = (u16*)w;   w += (size_t)NTOK * DIM * 2;          // 6.3 MB
  u16*   qkvB  = (u16*)w;                                         // 18.9 MB (union)
  u16*   mid   = (u16*)w;   w += (size_t)NTOK * 3072 * 2;         // 25.2 MB union
  u16*   attnb = (u16*)w;   w += (size_t)NTOK * DIM * 2;          // 6.3 MB
  float* x2    = (float*)w; w += (size_t)NTOK * DIM * 4;          // 12.6 MB
  u16*   vTb   = (u16*)w;   w += (size_t)NTOK * DIM * 2;          // 6.3 MB
  u16*   qkvwt = (u16*)w;   w += (size_t)DIM * 2304 * 2;
  u16*   projwt= (u16*)w;   w += (size_t)DIM * DIM * 2;
  u16*   l1wt  = (u16*)w;   w += (size_t)DIM * 3072 * 2;
  u16*   l2wt  = (u16*)w;   w += (size_t)3072 * DIM * 2;
  float* Pbuf  = (float*)w; w += (size_t)NTOK * DIM * 4;          // 12.6 MB (split-K P1)

  wcvt_all<<<6912, 256, 0, stream>>>(qkvw, projw, l1w, l2w,
                                     qkvwt, projwt, l1wt, l2wt);

  ln_kernel<<<NTOK, 256, 0, stream>>>(x, ln1w, ln1b, h);
  // qkv GEMM with fused V-transpose epilogue (vtr kernel deleted)
  bgemm_kernel<<<dim3(2304 / 128, NTOK / 128), 256, 0, stream>>>(
      h, qkvwt, qkvbi, qkvB, NTOK, 2304, DIM, 0, 1, vTb, 1);
  attn_kernel<<<dim3(SEQ / 64, HEADS, 2), 512, 0, stream>>>(qkvB, vTb, attnb);

  // proj: split-K x2 -> x2 + Pbuf; fused reduce(+bias+x residual) + LN2
  bgemm_splitk<<<dim3(DIM / 64, NTOK / 128, 2), 256, 0, stream>>>(
      attnb, projwt, x2, Pbuf, NTOK, DIM, DIM);
  redln_kernel<<<NTOK, 256, 0, stream>>>(x2, Pbuf, projb, x, x2, ln2w, ln2b, h);

  bgemm_kernel<<<dim3(3072 / 128, NTOK / 128), 256, 0, stream>>>(
      h, l1wt, l1b, mid, NTOK, 3072, DIM, 1, 0, vTb, 0);

  // lin2: split-K x2 -> out + Pbuf; reduce adds bias + x2 residual
  bgemm_splitk<<<dim3(DIM / 64, NTOK / 128, 2), 256, 0, stream>>>(
      mid, l2wt, out, Pbuf, NTOK, DIM, 3072);
  red_kernel<<<NTOK * DIM / 1024, 256, 0, stream>>>(out, Pbuf, l2b, x2, out, DIM);
}